// Round 5
// baseline (1195.706 us; speedup 1.0000x reference)
//
#include <hip/hip_runtime.h>

#define N_NODES 100000
#define N_EDGES 1600000
#define D 64

#define NB 2048                 // buckets (power of 2)
#define BUCKET_W 49             // nodes per bucket
#define NB_USED ((N_NODES + BUCKET_W - 1) / BUCKET_W)   // 2041
#define AB_BLOCKS 256
#define CHUNK ((N_EDGES + AB_BLOCKS - 1) / AB_BLOCKS)   // 6250
#define N8 (N_NODES * 8)        // elements per feature-slice plane

// ---------------- zero int buffer ----------------
__global__ void zero_int(int* __restrict__ p, int n) {
    int i = blockIdx.x * blockDim.x + threadIdx.x;
    if (i < n) p[i] = 0;
}

// ---------------- pass A: histogram dst into (bucket, group) ----------------
__global__ __launch_bounds__(256) void bucket_count(const int* __restrict__ dst,
                                                    int* __restrict__ gcount) {
    __shared__ int h[NB];
    for (int i = threadIdx.x; i < NB; i += 256) h[i] = 0;
    __syncthreads();
    const int blk = blockIdx.x;
    const int g = blk & 7;
    const int beg = blk * CHUNK;
    const int end = min(beg + CHUNK, N_EDGES);
    for (int e = beg + threadIdx.x; e < end; e += 256)
        atomicAdd(&h[dst[e] / BUCKET_W], 1);
    __syncthreads();
    for (int i = threadIdx.x; i < NB; i += 256) {
        int v = h[i];
        if (v) atomicAdd(&gcount[i * 8 + g], v);
    }
}

// ---------------- scan of 16384 (bucket,group) counts -> subbase & cursor ----------------
__global__ __launch_bounds__(1024) void scan16k(const int* __restrict__ gcount,
                                                int* __restrict__ subbase,
                                                int* __restrict__ cursor) {
    __shared__ int s[1024];
    const int t = threadIdx.x;
    int loc[16];
    int sum = 0;
#pragma unroll
    for (int i = 0; i < 16; ++i) { loc[i] = gcount[t * 16 + i]; sum += loc[i]; }
    s[t] = sum;
    __syncthreads();
    for (int off = 1; off < 1024; off <<= 1) {
        int u = (t >= off) ? s[t - off] : 0;
        __syncthreads();
        s[t] += u;
        __syncthreads();
    }
    int excl = s[t] - sum;
#pragma unroll
    for (int i = 0; i < 16; ++i) {
        int idx = t * 16 + i;
        subbase[idx] = excl;
        cursor[idx] = excl;
        excl += loc[i];
    }
    if (t == 1023) subbase[16384] = excl;
}

// ---------------- pass B: scatter packed edges into (bucket,group) sub-regions ----------------
__global__ __launch_bounds__(256) void partition_edges(const int* __restrict__ src,
                                                       const int* __restrict__ dst,
                                                       int* __restrict__ cursor,
                                                       int* __restrict__ part) {
    const int blk = blockIdx.x;
    const int g = blk & 7;
    const int beg = blk * CHUNK;
    const int end = min(beg + CHUNK, N_EDGES);
    for (int e = beg + threadIdx.x; e < end; e += 256) {
        const int d = dst[e];
        const int s = src[e];
        const int b = d / BUCKET_W;
        const int local = d - b * BUCKET_W;
        const int pos = atomicAdd(&cursor[b * 8 + g], 1);
        part[pos] = (s << 6) | local;
    }
}

// ---------------- per-bucket degree -> dinv ----------------
__global__ __launch_bounds__(256) void dinv_pass(const int* __restrict__ subbase,
                                                 const int* __restrict__ part,
                                                 float* __restrict__ dinv) {
    __shared__ int hist[BUCKET_W];
    const int b = blockIdx.x;
    const int base = subbase[b * 8];
    const int cnt = subbase[(b + 1) * 8] - base;
    const int n0 = b * BUCKET_W;
    const int nn = min(N_NODES - n0, BUCKET_W);
    const int t = threadIdx.x;
    if (t < BUCKET_W) hist[t] = 0;
    __syncthreads();
    for (int i = t; i < cnt; i += 256) atomicAdd(&hist[part[base + i] & 63], 1);
    __syncthreads();
    if (t < nn) dinv[n0 + t] = rsqrtf((float)hist[t] + 1.0f);
}

// ---------------- transpose x [N][64] -> xs [8][N][8] (slice-major) ----------------
__global__ void transpose_x(const float* __restrict__ x, float* __restrict__ xs) {
    int t = blockIdx.x * blockDim.x + threadIdx.x;
    if (t >= N_NODES * 8) return;
    const int node = t >> 3, slice = t & 7;
    const float4* xr = (const float4*)(x + (size_t)node * 64 + slice * 8);
    float4* xw = (float4*)(xs + (size_t)slice * N8 + node * 8);
    xw[0] = xr[0];
    xw[1] = xr[1];
}

// ---------------- sliced aggregation: aggs[slice][d][f] = dv*sum + dv^2*x[d][f] ----------------
// blockIdx = bucket*8 + slice  ->  blockIdx%8 == slice pins each slice to one XCD,
// so the random x-gathers hit a 3.2MB slice that is L2-resident per XCD.
__global__ __launch_bounds__(256) void agg_slice(const int* __restrict__ subbase,
                                                 const int* __restrict__ part,
                                                 const float* __restrict__ dinv,
                                                 const float* __restrict__ xs,
                                                 float* __restrict__ aggs) {
    const int slice = blockIdx.x & 7;
    const int b = blockIdx.x >> 3;
    const int base = subbase[b * 8];
    const int cnt = subbase[(b + 1) * 8] - base;
    const int n0 = b * BUCKET_W;
    const int nn = min(N_NODES - n0, BUCKET_W);
    const int f = threadIdx.x & 7;    // feature within slice
    const int es = threadIdx.x >> 3;  // edge slot 0..31
    __shared__ float acc[BUCKET_W * 9];   // pad 8->9 to spread LDS banks
    for (int i = threadIdx.x; i < BUCKET_W * 9; i += 256) acc[i] = 0.f;
    __syncthreads();
    const float* xsl = xs + (size_t)slice * N8;
    for (int j = es; j < cnt; j += 32) {
        const int p = part[base + j];
        const int s = p >> 6;
        const float w = dinv[s];
        atomicAdd(&acc[(p & 63) * 9 + f], w * xsl[(size_t)s * 8 + f]);
    }
    __syncthreads();
    float* asl = aggs + (size_t)slice * N8;
    for (int i = threadIdx.x; i < nn * 8; i += 256) {
        const int local = i >> 3, ff = i & 7;
        const int node = n0 + local;
        const float dv = dinv[node];
        asl[(size_t)node * 8 + ff] =
            fmaf(dv * dv, xsl[(size_t)node * 8 + ff], dv * acc[local * 9 + ff]);
    }
}

// ---------------- GEMM: out = relu(agg @ W + b), one wave per node ----------------
__device__ __forceinline__ float rlane_f(float v, int l) {
    return __int_as_float(__builtin_amdgcn_readlane(__float_as_int(v), l));
}

template <bool SLICE_OUT>
__global__ __launch_bounds__(256) void gemm64(const float* __restrict__ aggs,
                                              const float* __restrict__ W,
                                              const float* __restrict__ bias,
                                              float* __restrict__ out, int n) {
    const int lane = threadIdx.x & 63;
    const int gwave = (blockIdx.x * blockDim.x + threadIdx.x) >> 6;
    const int nwaves = (gridDim.x * blockDim.x) >> 6;
    float wcol[64];
#pragma unroll
    for (int k = 0; k < 64; ++k) wcol[k] = W[k * 64 + lane];
    const float bv = bias[lane];
    const int slice = lane >> 3, f = lane & 7;
    const float* ap = aggs + (size_t)slice * N8 + f;  // lane l holds feature l

    for (int nd = gwave; nd < n; nd += nwaves) {
        const float a = ap[(size_t)nd * 8];
        float g0 = 0.f, g1 = 0.f, g2 = 0.f, g3 = 0.f;
#pragma unroll
        for (int k = 0; k < 64; k += 4) {
            g0 = fmaf(rlane_f(a, k + 0), wcol[k + 0], g0);
            g1 = fmaf(rlane_f(a, k + 1), wcol[k + 1], g1);
            g2 = fmaf(rlane_f(a, k + 2), wcol[k + 2], g2);
            g3 = fmaf(rlane_f(a, k + 3), wcol[k + 3], g3);
        }
        const float r = fmaxf((g0 + g1) + (g2 + g3) + bv, 0.f);
        if (SLICE_OUT)
            out[(size_t)slice * N8 + (size_t)nd * 8 + f] = r;  // slice-major for next layer
        else
            out[(size_t)nd * 64 + lane] = r;                   // row-major final output
    }
}

extern "C" void kernel_launch(void* const* d_in, const int* in_sizes, int n_in,
                              void* d_out, int out_size, void* d_ws, size_t ws_size,
                              hipStream_t stream) {
    const float* feature = (const float*)d_in[0];
    const int*   edges   = (const int*)d_in[1];   // [2, E] flat: src then dst
    const float* W1      = (const float*)d_in[2];
    const float* b1      = (const float*)d_in[3];
    const float* W2      = (const float*)d_in[4];
    const float* b2      = (const float*)d_in[5];
    float* out = (float*)d_out;

    const int* src = edges;
    const int* dst = edges + N_EDGES;

    // workspace layout
    char* w = (char*)d_ws;
    int*   gcount  = (int*)w;   w += sizeof(int) * (NB * 8);        // 16384
    int*   subbase = (int*)w;   w += sizeof(int) * (NB * 8 + 1);    // 16385
    int*   cursor  = (int*)w;   w += sizeof(int) * (NB * 8);
    float* dinv    = (float*)w; w += sizeof(float) * (N_NODES);
    int*   part    = (int*)w;   w += sizeof(int) * (N_EDGES);
    float* xs      = (float*)w; w += sizeof(float) * ((size_t)8 * N8);  // 25.6MB
    float* y1s     = (float*)w; w += sizeof(float) * ((size_t)8 * N8);  // 25.6MB
    float* aggs    = (float*)w; w += sizeof(float) * ((size_t)8 * N8);  // 25.6MB

    // ---- partition build (once, shared by both layers) ----
    zero_int<<<(NB * 8 + 255) / 256, 256, 0, stream>>>(gcount, NB * 8);
    bucket_count<<<AB_BLOCKS, 256, 0, stream>>>(dst, gcount);
    scan16k<<<1, 1024, 0, stream>>>(gcount, subbase, cursor);
    partition_edges<<<AB_BLOCKS, 256, 0, stream>>>(src, dst, cursor, part);
    dinv_pass<<<NB_USED, 256, 0, stream>>>(subbase, part, dinv);
    transpose_x<<<(N_NODES * 8 + 255) / 256, 256, 0, stream>>>(feature, xs);

    // ---- layer 1 ----
    agg_slice<<<NB_USED * 8, 256, 0, stream>>>(subbase, part, dinv, xs, aggs);
    gemm64<true><<<2048, 256, 0, stream>>>(aggs, W1, b1, y1s, N_NODES);

    // ---- layer 2 ----
    agg_slice<<<NB_USED * 8, 256, 0, stream>>>(subbase, part, dinv, y1s, aggs);
    gemm64<false><<<2048, 256, 0, stream>>>(aggs, W2, b2, out, N_NODES);
}

// Round 6
// 599.603 us; speedup vs baseline: 1.9942x; 1.9942x over previous
//
#include <hip/hip_runtime.h>

#define N_NODES 100000
#define N_EDGES 1600000
#define D 64

#define NB 2048                 // buckets (power of 2)
#define BUCKET_W 49             // nodes per bucket
#define NB_USED ((N_NODES + BUCKET_W - 1) / BUCKET_W)   // 2041
#define AB_BLOCKS 256
#define CHUNK ((N_EDGES + AB_BLOCKS - 1) / AB_BLOCKS)   // 6250
#define CCAP 1536               // max edges per bucket (mean 784, sd ~28)
#define N8 (N_NODES * 8)        // elements per feature-slice plane

// ---------------- zero int buffer ----------------
__global__ void zero_int(int* __restrict__ p, int n) {
    int i = blockIdx.x * blockDim.x + threadIdx.x;
    if (i < n) p[i] = 0;
}

// ---------------- pass A: histogram dst into (bucket, group) ----------------
__global__ __launch_bounds__(256) void bucket_count(const int* __restrict__ dst,
                                                    int* __restrict__ gcount) {
    __shared__ int h[NB];
    for (int i = threadIdx.x; i < NB; i += 256) h[i] = 0;
    __syncthreads();
    const int blk = blockIdx.x;
    const int g = blk & 7;
    const int beg = blk * CHUNK;
    const int end = min(beg + CHUNK, N_EDGES);
    for (int e = beg + threadIdx.x; e < end; e += 256)
        atomicAdd(&h[dst[e] / BUCKET_W], 1);
    __syncthreads();
    for (int i = threadIdx.x; i < NB; i += 256) {
        int v = h[i];
        if (v) atomicAdd(&gcount[i * 8 + g], v);
    }
}

// ---------------- scan of 16384 (bucket,group) counts -> subbase & cursor ----------------
__global__ __launch_bounds__(1024) void scan16k(const int* __restrict__ gcount,
                                                int* __restrict__ subbase,
                                                int* __restrict__ cursor) {
    __shared__ int s[1024];
    const int t = threadIdx.x;
    int loc[16];
    int sum = 0;
#pragma unroll
    for (int i = 0; i < 16; ++i) { loc[i] = gcount[t * 16 + i]; sum += loc[i]; }
    s[t] = sum;
    __syncthreads();
    for (int off = 1; off < 1024; off <<= 1) {
        int u = (t >= off) ? s[t - off] : 0;
        __syncthreads();
        s[t] += u;
        __syncthreads();
    }
    int excl = s[t] - sum;
#pragma unroll
    for (int i = 0; i < 16; ++i) {
        int idx = t * 16 + i;
        subbase[idx] = excl;
        cursor[idx] = excl;
        excl += loc[i];
    }
    if (t == 1023) subbase[16384] = excl;
}

// ---------------- pass B: scatter packed edges into (bucket,group) sub-regions ----------------
__global__ __launch_bounds__(256) void partition_edges(const int* __restrict__ src,
                                                       const int* __restrict__ dst,
                                                       int* __restrict__ cursor,
                                                       int* __restrict__ part) {
    const int blk = blockIdx.x;
    const int g = blk & 7;
    const int beg = blk * CHUNK;
    const int end = min(beg + CHUNK, N_EDGES);
    for (int e = beg + threadIdx.x; e < end; e += 256) {
        const int d = dst[e];
        const int s = src[e];
        const int b = d / BUCKET_W;
        const int local = d - b * BUCKET_W;
        const int pos = atomicAdd(&cursor[b * 8 + g], 1);
        part[pos] = (s << 6) | local;
    }
}

// ---------------- pass C: per-bucket counting sort -> col, rowptr, dinv ----------------
__global__ __launch_bounds__(256) void bucket_csr(const int* __restrict__ subbase,
                                                  const int* __restrict__ part,
                                                  int* __restrict__ col,
                                                  int* __restrict__ rowptr,
                                                  float* __restrict__ dinv) {
    __shared__ int ed[CCAP];
    __shared__ int hist[BUCKET_W];
    __shared__ int offs[BUCKET_W];
    __shared__ int lcur[BUCKET_W];
    const int b = blockIdx.x;
    const int base = subbase[b * 8];
    const int cnt = min(subbase[(b + 1) * 8] - base, CCAP);
    const int n0 = b * BUCKET_W;
    const int nn = min(N_NODES - n0, BUCKET_W);
    const int t = threadIdx.x;

    if (t < BUCKET_W) hist[t] = 0;
    for (int i = t; i < cnt; i += 256) ed[i] = part[base + i];
    __syncthreads();
    for (int i = t; i < cnt; i += 256) atomicAdd(&hist[ed[i] & 63], 1);
    __syncthreads();
    if (t == 0) {
        int a = 0;
        for (int i = 0; i < nn; ++i) { offs[i] = a; lcur[i] = a; a += hist[i]; }
    }
    __syncthreads();
    if (t < nn) {
        rowptr[n0 + t] = base + offs[t];
        dinv[n0 + t] = rsqrtf((float)hist[t] + 1.0f);
        if (b == NB_USED - 1 && t == 0) rowptr[N_NODES] = N_EDGES;
    }
    for (int i = t; i < cnt; i += 256) {
        const int p = ed[i];
        const int pos = atomicAdd(&lcur[p & 63], 1);
        col[base + pos] = p >> 6;
    }
}

// ---------------- transpose x [N][64] -> xs [8][N][8] (slice-major) ----------------
__global__ void transpose_x(const float* __restrict__ x, float* __restrict__ xs) {
    int t = blockIdx.x * blockDim.x + threadIdx.x;
    if (t >= N_NODES * 8) return;
    const int node = t >> 3, slice = t & 7;
    const float4* xr = (const float4*)(x + (size_t)node * 64 + slice * 8);
    float4* xw = (float4*)(xs + (size_t)slice * N8 + node * 8);
    xw[0] = xr[0];
    xw[1] = xr[1];
}

// ---------------- sliced aggregation, atomic-free ----------------
// blockIdx = k*8 + g  ->  blockIdx%8 == slice g pins each 3.2MB slice to one XCD L2.
// One wave per (node, slice): 16 edge-slots x 4 float2-feature lanes, register
// accumulate, shfl_xor reduce. No LDS, no atomics.
__global__ __launch_bounds__(256) void agg_sliced(const int* __restrict__ rowptr,
                                                  const int* __restrict__ col,
                                                  const float* __restrict__ dinv,
                                                  const float* __restrict__ xs,
                                                  float* __restrict__ aggs) {
    const int g = blockIdx.x & 7;
    const int k = blockIdx.x >> 3;
    const int nd = k * 4 + (threadIdx.x >> 6);
    if (nd >= N_NODES) return;
    const int lane = threadIdx.x & 63;
    const int es = lane >> 2;   // edge slot 0..15
    const int f2 = lane & 3;    // float2 pair 0..3

    const float* xsl = xs + (size_t)g * N8;
    const int beg = rowptr[nd];
    const int end = rowptr[nd + 1];

    float a0 = 0.f, a1 = 0.f;
    for (int j = beg; j < end; j += 16) {
        const int idx = j + es;
        const bool valid = idx < end;
        const int s = col[valid ? idx : (end - 1)];
        const float w = valid ? dinv[s] : 0.f;
        const float2 v = *(const float2*)(xsl + (size_t)s * 8 + f2 * 2);
        a0 = fmaf(v.x, w, a0);
        a1 = fmaf(v.y, w, a1);
    }
#pragma unroll
    for (int off = 4; off < 64; off <<= 1) {
        a0 += __shfl_xor(a0, off, 64);
        a1 += __shfl_xor(a1, off, 64);
    }
    if (es == 0) {
        const float dv = dinv[nd];
        const float2 xn = *(const float2*)(xsl + (size_t)nd * 8 + f2 * 2);
        float2 r;
        r.x = fmaf(dv * dv, xn.x, dv * a0);
        r.y = fmaf(dv * dv, xn.y, dv * a1);
        *(float2*)(aggs + (size_t)g * N8 + (size_t)nd * 8 + f2 * 2) = r;
    }
}

// ---------------- GEMM: out = relu(agg @ W + b), one wave per node ----------------
__device__ __forceinline__ float rlane_f(float v, int l) {
    return __int_as_float(__builtin_amdgcn_readlane(__float_as_int(v), l));
}

template <bool SLICE_OUT>
__global__ __launch_bounds__(256) void gemm64(const float* __restrict__ aggs,
                                              const float* __restrict__ W,
                                              const float* __restrict__ bias,
                                              float* __restrict__ out, int n) {
    const int lane = threadIdx.x & 63;
    const int gwave = (blockIdx.x * blockDim.x + threadIdx.x) >> 6;
    const int nwaves = (gridDim.x * blockDim.x) >> 6;
    float wcol[64];
#pragma unroll
    for (int k = 0; k < 64; ++k) wcol[k] = W[k * 64 + lane];
    const float bv = bias[lane];
    const int slice = lane >> 3, f = lane & 7;
    const float* ap = aggs + (size_t)slice * N8 + f;  // lane l holds feature l

    for (int nd = gwave; nd < n; nd += nwaves) {
        const float a = ap[(size_t)nd * 8];
        float g0 = 0.f, g1 = 0.f, g2 = 0.f, g3 = 0.f;
#pragma unroll
        for (int k = 0; k < 64; k += 4) {
            g0 = fmaf(rlane_f(a, k + 0), wcol[k + 0], g0);
            g1 = fmaf(rlane_f(a, k + 1), wcol[k + 1], g1);
            g2 = fmaf(rlane_f(a, k + 2), wcol[k + 2], g2);
            g3 = fmaf(rlane_f(a, k + 3), wcol[k + 3], g3);
        }
        const float r = fmaxf((g0 + g1) + (g2 + g3) + bv, 0.f);
        if (SLICE_OUT)
            out[(size_t)slice * N8 + (size_t)nd * 8 + f] = r;  // slice-major for next layer
        else
            out[(size_t)nd * 64 + lane] = r;                   // row-major final output
    }
}

extern "C" void kernel_launch(void* const* d_in, const int* in_sizes, int n_in,
                              void* d_out, int out_size, void* d_ws, size_t ws_size,
                              hipStream_t stream) {
    const float* feature = (const float*)d_in[0];
    const int*   edges   = (const int*)d_in[1];   // [2, E] flat: src then dst
    const float* W1      = (const float*)d_in[2];
    const float* b1      = (const float*)d_in[3];
    const float* W2      = (const float*)d_in[4];
    const float* b2      = (const float*)d_in[5];
    float* out = (float*)d_out;

    const int* src = edges;
    const int* dst = edges + N_EDGES;

    // workspace layout
    char* w = (char*)d_ws;
    int*   gcount  = (int*)w;   w += sizeof(int) * (NB * 8);        // 16384
    int*   subbase = (int*)w;   w += sizeof(int) * (NB * 8 + 1);    // 16385
    int*   cursor  = (int*)w;   w += sizeof(int) * (NB * 8);
    int*   rowptr  = (int*)w;   w += sizeof(int) * (N_NODES + 1);
    float* dinv    = (float*)w; w += sizeof(float) * (N_NODES);
    int*   part    = (int*)w;   w += sizeof(int) * (N_EDGES);
    int*   colA    = (int*)w;   w += sizeof(int) * (N_EDGES);
    float* xs      = (float*)w; w += sizeof(float) * ((size_t)8 * N8);  // 25.6MB
    float* y1s     = (float*)w; w += sizeof(float) * ((size_t)8 * N8);  // 25.6MB
    float* aggs    = (float*)w; w += sizeof(float) * ((size_t)8 * N8);  // 25.6MB

    // ---- partition + CSR build (once, shared by both layers) ----
    zero_int<<<(NB * 8 + 255) / 256, 256, 0, stream>>>(gcount, NB * 8);
    bucket_count<<<AB_BLOCKS, 256, 0, stream>>>(dst, gcount);
    scan16k<<<1, 1024, 0, stream>>>(gcount, subbase, cursor);
    partition_edges<<<AB_BLOCKS, 256, 0, stream>>>(src, dst, cursor, part);
    bucket_csr<<<NB_USED, 256, 0, stream>>>(subbase, part, colA, rowptr, dinv);
    transpose_x<<<(N_NODES * 8 + 255) / 256, 256, 0, stream>>>(feature, xs);

    const int agg_grid = ((N_NODES + 3) / 4) * 8;   // 25000 node-chunks x 8 slices

    // ---- layer 1 ----
    agg_sliced<<<agg_grid, 256, 0, stream>>>(rowptr, colA, dinv, xs, aggs);
    gemm64<true><<<2048, 256, 0, stream>>>(aggs, W1, b1, y1s, N_NODES);

    // ---- layer 2 ----
    agg_sliced<<<agg_grid, 256, 0, stream>>>(rowptr, colA, dinv, y1s, aggs);
    gemm64<false><<<2048, 256, 0, stream>>>(aggs, W2, b2, out, N_NODES);
}

// Round 7
// 310.581 us; speedup vs baseline: 3.8499x; 1.9306x over previous
//
#include <hip/hip_runtime.h>

#define N_NODES 100000
#define N_EDGES 1600000
#define D 64

#define NB 2048                 // buckets (power of 2)
#define BUCKET_W 49             // nodes per bucket
#define NB_USED ((N_NODES + BUCKET_W - 1) / BUCKET_W)   // 2041
#define AB_BLOCKS 256
#define CHUNK ((N_EDGES + AB_BLOCKS - 1) / AB_BLOCKS)   // 6250
#define CCAP 1536               // max edges per bucket (mean 784, sd ~28)

// ---------------- zero int buffer ----------------
__global__ void zero_int(int* __restrict__ p, int n) {
    int i = blockIdx.x * blockDim.x + threadIdx.x;
    if (i < n) p[i] = 0;
}

// ---------------- pass A: histogram dst into (bucket, group) ----------------
__global__ __launch_bounds__(256) void bucket_count(const int* __restrict__ dst,
                                                    int* __restrict__ gcount) {
    __shared__ int h[NB];
    for (int i = threadIdx.x; i < NB; i += 256) h[i] = 0;
    __syncthreads();
    const int blk = blockIdx.x;
    const int g = blk & 7;
    const int beg = blk * CHUNK;
    const int end = min(beg + CHUNK, N_EDGES);
    for (int e = beg + threadIdx.x; e < end; e += 256)
        atomicAdd(&h[dst[e] / BUCKET_W], 1);
    __syncthreads();
    for (int i = threadIdx.x; i < NB; i += 256) {
        int v = h[i];
        if (v) atomicAdd(&gcount[i * 8 + g], v);
    }
}

// ---------------- scan of 16384 (bucket,group) counts -> subbase & cursor ----------------
__global__ __launch_bounds__(1024) void scan16k(const int* __restrict__ gcount,
                                                int* __restrict__ subbase,
                                                int* __restrict__ cursor) {
    __shared__ int s[1024];
    const int t = threadIdx.x;
    int loc[16];
    int sum = 0;
#pragma unroll
    for (int i = 0; i < 16; ++i) { loc[i] = gcount[t * 16 + i]; sum += loc[i]; }
    s[t] = sum;
    __syncthreads();
    for (int off = 1; off < 1024; off <<= 1) {
        int u = (t >= off) ? s[t - off] : 0;
        __syncthreads();
        s[t] += u;
        __syncthreads();
    }
    int excl = s[t] - sum;
#pragma unroll
    for (int i = 0; i < 16; ++i) {
        int idx = t * 16 + i;
        subbase[idx] = excl;
        cursor[idx] = excl;
        excl += loc[i];
    }
    if (t == 1023) subbase[16384] = excl;
}

// ---------------- pass B: scatter packed edges into (bucket,group) sub-regions ----------------
__global__ __launch_bounds__(256) void partition_edges(const int* __restrict__ src,
                                                       const int* __restrict__ dst,
                                                       int* __restrict__ cursor,
                                                       int* __restrict__ part) {
    const int blk = blockIdx.x;
    const int g = blk & 7;
    const int beg = blk * CHUNK;
    const int end = min(beg + CHUNK, N_EDGES);
    for (int e = beg + threadIdx.x; e < end; e += 256) {
        const int d = dst[e];
        const int s = src[e];
        const int b = d / BUCKET_W;
        const int local = d - b * BUCKET_W;
        const int pos = atomicAdd(&cursor[b * 8 + g], 1);
        part[pos] = (s << 6) | local;
    }
}

// ---------------- per-bucket degree -> dinv, selfw ----------------
__global__ __launch_bounds__(256) void dinv_pass(const int* __restrict__ subbase,
                                                 const int* __restrict__ part,
                                                 float* __restrict__ dinv,
                                                 float* __restrict__ selfw) {
    __shared__ int hist[BUCKET_W];
    const int b = blockIdx.x;
    const int base = subbase[b * 8];
    const int cnt = subbase[(b + 1) * 8] - base;
    const int n0 = b * BUCKET_W;
    const int nn = min(N_NODES - n0, BUCKET_W);
    const int t = threadIdx.x;
    if (t < BUCKET_W) hist[t] = 0;
    __syncthreads();
    for (int i = t; i < cnt; i += 256) atomicAdd(&hist[part[base + i] & 63], 1);
    __syncthreads();
    if (t < nn) {
        const float deg = (float)hist[t] + 1.0f;
        dinv[n0 + t] = rsqrtf(deg);
        selfw[n0 + t] = 1.0f / deg;
    }
}

// ---------------- pass C: per-bucket counting sort -> pairs(col, enorm), rowptr ----------------
__global__ __launch_bounds__(256) void bucket_pairs(const int* __restrict__ subbase,
                                                    const int* __restrict__ part,
                                                    const float* __restrict__ dinv,
                                                    int2* __restrict__ pairs,
                                                    int* __restrict__ rowptr) {
    __shared__ int ed[CCAP];
    __shared__ int hist[BUCKET_W];
    __shared__ int offs[BUCKET_W];
    __shared__ int lcur[BUCKET_W];
    const int b = blockIdx.x;
    const int base = subbase[b * 8];
    const int cnt = min(subbase[(b + 1) * 8] - base, CCAP);
    const int n0 = b * BUCKET_W;
    const int nn = min(N_NODES - n0, BUCKET_W);
    const int t = threadIdx.x;

    if (t < BUCKET_W) hist[t] = 0;
    for (int i = t; i < cnt; i += 256) ed[i] = part[base + i];
    __syncthreads();
    for (int i = t; i < cnt; i += 256) atomicAdd(&hist[ed[i] & 63], 1);
    __syncthreads();
    if (t == 0) {
        int a = 0;
        for (int i = 0; i < nn; ++i) { offs[i] = a; lcur[i] = a; a += hist[i]; }
    }
    __syncthreads();
    if (t < nn) {
        rowptr[n0 + t] = base + offs[t];
        if (b == NB_USED - 1 && t == 0) rowptr[N_NODES] = N_EDGES;
    }
    __syncthreads();
    for (int i = t; i < cnt; i += 256) {
        const int p = ed[i];
        const int local = p & 63;
        const int s = p >> 6;
        const int pos = atomicAdd(&lcur[local], 1);
        const float en = dinv[s] * dinv[n0 + local];
        pairs[base + pos] = make_int2(s, __float_as_int(en));
    }
}

// ---------------- aggregation: agg[nd] = sum enorm*x[src] + selfw*x[nd] ----------------
// One wave per node, lane = feature. Per edge: one 256B row gather (4 lines),
// edge metadata via coalesced int2 load + readlane broadcast. No atomics, no LDS.
__device__ __forceinline__ float rlane_f(int v, int l) {
    return __int_as_float(__builtin_amdgcn_readlane(v, l));
}
__device__ __forceinline__ int rlane_i(int v, int l) {
    return __builtin_amdgcn_readlane(v, l);
}

__global__ __launch_bounds__(256) void agg_rows(const float* __restrict__ x,
                                                const int* __restrict__ rowptr,
                                                const int2* __restrict__ pairs,
                                                const float* __restrict__ selfw,
                                                float* __restrict__ agg, int n) {
    const int nd = blockIdx.x * 4 + (threadIdx.x >> 6);
    if (nd >= n) return;
    const int lane = threadIdx.x & 63;
    const int beg = rowptr[nd];
    const int end = rowptr[nd + 1];

    float a0 = 0.f, a1 = 0.f, a2 = 0.f, a3 = 0.f;
    for (int j = beg; j < end; j += 64) {
        const int chunk = min(end - j, 64);
        int2 pr = make_int2(0, 0);
        if (lane < chunk) pr = pairs[j + lane];   // coalesced 8B/lane
        int t = 0;
        for (; t + 7 < chunk; t += 8) {
            const int   s0 = rlane_i(pr.x, t + 0), s1 = rlane_i(pr.x, t + 1);
            const int   s2 = rlane_i(pr.x, t + 2), s3 = rlane_i(pr.x, t + 3);
            const int   s4 = rlane_i(pr.x, t + 4), s5 = rlane_i(pr.x, t + 5);
            const int   s6 = rlane_i(pr.x, t + 6), s7 = rlane_i(pr.x, t + 7);
            const float w0 = rlane_f(pr.y, t + 0), w1 = rlane_f(pr.y, t + 1);
            const float w2 = rlane_f(pr.y, t + 2), w3 = rlane_f(pr.y, t + 3);
            const float w4 = rlane_f(pr.y, t + 4), w5 = rlane_f(pr.y, t + 5);
            const float w6 = rlane_f(pr.y, t + 6), w7 = rlane_f(pr.y, t + 7);
            a0 = fmaf(x[(size_t)s0 * D + lane], w0, a0);
            a1 = fmaf(x[(size_t)s1 * D + lane], w1, a1);
            a2 = fmaf(x[(size_t)s2 * D + lane], w2, a2);
            a3 = fmaf(x[(size_t)s3 * D + lane], w3, a3);
            a0 = fmaf(x[(size_t)s4 * D + lane], w4, a0);
            a1 = fmaf(x[(size_t)s5 * D + lane], w5, a1);
            a2 = fmaf(x[(size_t)s6 * D + lane], w6, a2);
            a3 = fmaf(x[(size_t)s7 * D + lane], w7, a3);
        }
        for (; t < chunk; ++t) {
            const int   s0 = rlane_i(pr.x, t);
            const float w0 = rlane_f(pr.y, t);
            a0 = fmaf(x[(size_t)s0 * D + lane], w0, a0);
        }
    }
    const float a = (a0 + a1) + (a2 + a3) + selfw[nd] * x[(size_t)nd * D + lane];
    agg[(size_t)nd * D + lane] = a;
}

// ---------------- GEMM: out = relu(agg @ W + b), one wave per node ----------------
__device__ __forceinline__ float rlane_ff(float v, int l) {
    return __int_as_float(__builtin_amdgcn_readlane(__float_as_int(v), l));
}

__global__ __launch_bounds__(256) void gemm64(const float* __restrict__ aggs,
                                              const float* __restrict__ W,
                                              const float* __restrict__ bias,
                                              float* __restrict__ out, int n) {
    const int lane = threadIdx.x & 63;
    const int gwave = (blockIdx.x * blockDim.x + threadIdx.x) >> 6;
    const int nwaves = (gridDim.x * blockDim.x) >> 6;
    float wcol[64];
#pragma unroll
    for (int k = 0; k < 64; ++k) wcol[k] = W[k * 64 + lane];
    const float bv = bias[lane];

    for (int nd = gwave; nd < n; nd += nwaves) {
        const float a = aggs[(size_t)nd * D + lane];   // lane holds feature `lane`
        float g0 = 0.f, g1 = 0.f, g2 = 0.f, g3 = 0.f;
#pragma unroll
        for (int k = 0; k < 64; k += 4) {
            g0 = fmaf(rlane_ff(a, k + 0), wcol[k + 0], g0);
            g1 = fmaf(rlane_ff(a, k + 1), wcol[k + 1], g1);
            g2 = fmaf(rlane_ff(a, k + 2), wcol[k + 2], g2);
            g3 = fmaf(rlane_ff(a, k + 3), wcol[k + 3], g3);
        }
        out[(size_t)nd * D + lane] = fmaxf((g0 + g1) + (g2 + g3) + bv, 0.f);
    }
}

extern "C" void kernel_launch(void* const* d_in, const int* in_sizes, int n_in,
                              void* d_out, int out_size, void* d_ws, size_t ws_size,
                              hipStream_t stream) {
    const float* feature = (const float*)d_in[0];
    const int*   edges   = (const int*)d_in[1];   // [2, E] flat: src then dst
    const float* W1      = (const float*)d_in[2];
    const float* b1      = (const float*)d_in[3];
    const float* W2      = (const float*)d_in[4];
    const float* b2      = (const float*)d_in[5];
    float* out = (float*)d_out;

    const int* src = edges;
    const int* dst = edges + N_EDGES;

    // workspace layout
    char* w = (char*)d_ws;
    int*   gcount  = (int*)w;   w += sizeof(int) * (NB * 8);        // 16384
    int*   subbase = (int*)w;   w += sizeof(int) * (NB * 8 + 1);    // 16385
    int*   cursor  = (int*)w;   w += sizeof(int) * (NB * 8);
    int*   rowptr  = (int*)w;   w += sizeof(int) * (N_NODES + 1);
    float* dinv    = (float*)w; w += sizeof(float) * (N_NODES);
    float* selfw   = (float*)w; w += sizeof(float) * (N_NODES);
    int*   part    = (int*)w;   w += sizeof(int) * (N_EDGES);
    int2*  pairs   = (int2*)w;  w += sizeof(int2) * (N_EDGES);          // 12.8MB
    float* aggsA   = (float*)w; w += sizeof(float) * ((size_t)N_NODES * D);  // 25.6MB
    float* y1      = (float*)w; w += sizeof(float) * ((size_t)N_NODES * D);  // 25.6MB

    // ---- partition + packed-CSR build (once, shared by both layers) ----
    zero_int<<<(NB * 8 + 255) / 256, 256, 0, stream>>>(gcount, NB * 8);
    bucket_count<<<AB_BLOCKS, 256, 0, stream>>>(dst, gcount);
    scan16k<<<1, 1024, 0, stream>>>(gcount, subbase, cursor);
    partition_edges<<<AB_BLOCKS, 256, 0, stream>>>(src, dst, cursor, part);
    dinv_pass<<<NB_USED, 256, 0, stream>>>(subbase, part, dinv, selfw);
    bucket_pairs<<<NB_USED, 256, 0, stream>>>(subbase, part, dinv, pairs, rowptr);

    const int agg_blocks = (N_NODES + 3) / 4;

    // ---- layer 1 ----
    agg_rows<<<agg_blocks, 256, 0, stream>>>(feature, rowptr, pairs, selfw, aggsA, N_NODES);
    gemm64<<<2048, 256, 0, stream>>>(aggsA, W1, b1, y1, N_NODES);

    // ---- layer 2 ----
    agg_rows<<<agg_blocks, 256, 0, stream>>>(y1, rowptr, pairs, selfw, aggsA, N_NODES);
    gemm64<<<2048, 256, 0, stream>>>(aggsA, W2, b2, out, N_NODES);
}

// Round 9
// 276.838 us; speedup vs baseline: 4.3192x; 1.1219x over previous
//
#include <hip/hip_runtime.h>
#include <hip/hip_fp16.h>

#define N_NODES 100000
#define N_EDGES 1600000
#define D 64

#define NB 2048                 // buckets (power of 2)
#define BUCKET_W 49             // nodes per bucket
#define NB_USED ((N_NODES + BUCKET_W - 1) / BUCKET_W)   // 2041
#define AB_BLOCKS 256
#define CHUNK ((N_EDGES + AB_BLOCKS - 1) / AB_BLOCKS)   // 6250
#define CCAP 1536               // max edges per bucket (mean 784, sd ~28)

// ---------------- zero int buffer ----------------
__global__ void zero_int(int* __restrict__ p, int n) {
    int i = blockIdx.x * blockDim.x + threadIdx.x;
    if (i < n) p[i] = 0;
}

// ---------------- pass A: histogram dst into (bucket, group) ----------------
__global__ __launch_bounds__(256) void bucket_count(const int* __restrict__ dst,
                                                    int* __restrict__ gcount) {
    __shared__ int h[NB];
    for (int i = threadIdx.x; i < NB; i += 256) h[i] = 0;
    __syncthreads();
    const int blk = blockIdx.x;
    const int g = blk & 7;
    const int beg = blk * CHUNK;
    const int end = min(beg + CHUNK, N_EDGES);
    for (int e = beg + threadIdx.x; e < end; e += 256)
        atomicAdd(&h[dst[e] / BUCKET_W], 1);
    __syncthreads();
    for (int i = threadIdx.x; i < NB; i += 256) {
        int v = h[i];
        if (v) atomicAdd(&gcount[i * 8 + g], v);
    }
}

// ---------------- scan of 16384 (bucket,group) counts -> subbase & cursor ----------------
__global__ __launch_bounds__(1024) void scan16k(const int* __restrict__ gcount,
                                                int* __restrict__ subbase,
                                                int* __restrict__ cursor) {
    __shared__ int s[1024];
    const int t = threadIdx.x;
    int loc[16];
    int sum = 0;
#pragma unroll
    for (int i = 0; i < 16; ++i) { loc[i] = gcount[t * 16 + i]; sum += loc[i]; }
    s[t] = sum;
    __syncthreads();
    for (int off = 1; off < 1024; off <<= 1) {
        int u = (t >= off) ? s[t - off] : 0;
        __syncthreads();
        s[t] += u;
        __syncthreads();
    }
    int excl = s[t] - sum;
#pragma unroll
    for (int i = 0; i < 16; ++i) {
        int idx = t * 16 + i;
        subbase[idx] = excl;
        cursor[idx] = excl;
        excl += loc[i];
    }
    if (t == 1023) subbase[16384] = excl;
}

// ---------------- pass B: scatter packed edges into (bucket,group) sub-regions ----------------
__global__ __launch_bounds__(256) void partition_edges(const int* __restrict__ src,
                                                       const int* __restrict__ dst,
                                                       int* __restrict__ cursor,
                                                       int* __restrict__ part) {
    const int blk = blockIdx.x;
    const int g = blk & 7;
    const int beg = blk * CHUNK;
    const int end = min(beg + CHUNK, N_EDGES);
    for (int e = beg + threadIdx.x; e < end; e += 256) {
        const int d = dst[e];
        const int s = src[e];
        const int b = d / BUCKET_W;
        const int local = d - b * BUCKET_W;
        const int pos = atomicAdd(&cursor[b * 8 + g], 1);
        part[pos] = (s << 6) | local;
    }
}

// ---------------- pass C: per-bucket counting sort -> col, rowptr, dinv ----------------
__global__ __launch_bounds__(256) void bucket_csr(const int* __restrict__ subbase,
                                                  const int* __restrict__ part,
                                                  int* __restrict__ col,
                                                  int* __restrict__ rowptr,
                                                  float* __restrict__ dinv) {
    __shared__ int ed[CCAP];
    __shared__ int hist[BUCKET_W];
    __shared__ int offs[BUCKET_W];
    __shared__ int lcur[BUCKET_W];
    const int b = blockIdx.x;
    const int base = subbase[b * 8];
    const int cnt = min(subbase[(b + 1) * 8] - base, CCAP);
    const int n0 = b * BUCKET_W;
    const int nn = min(N_NODES - n0, BUCKET_W);
    const int t = threadIdx.x;

    if (t < BUCKET_W) hist[t] = 0;
    for (int i = t; i < cnt; i += 256) ed[i] = part[base + i];
    __syncthreads();
    for (int i = t; i < cnt; i += 256) atomicAdd(&hist[ed[i] & 63], 1);
    __syncthreads();
    if (t == 0) {
        int a = 0;
        for (int i = 0; i < nn; ++i) { offs[i] = a; lcur[i] = a; a += hist[i]; }
    }
    __syncthreads();
    if (t < nn) {
        rowptr[n0 + t] = base + offs[t];
        dinv[n0 + t] = rsqrtf((float)hist[t] + 1.0f);
        if (b == NB_USED - 1 && t == 0) rowptr[N_NODES] = N_EDGES;
    }
    __syncthreads();
    for (int i = t; i < cnt; i += 256) {
        const int p = ed[i];
        const int pos = atomicAdd(&lcur[p & 63], 1);
        col[base + pos] = p >> 6;
    }
}

// ---------------- xsc[n] = (half)(x[n] * dinv[n])  [row-major fp16] ----------------
__global__ void convert_scale(const float* __restrict__ x, const float* __restrict__ dinv,
                              __half* __restrict__ xh) {
    int t = blockIdx.x * blockDim.x + threadIdx.x;
    if (t >= N_NODES * 8) return;
    const int node = t >> 3, oct = t & 7;
    const float dv = dinv[node];
    const float2* xr = (const float2*)(x + (size_t)node * 64 + oct * 8);
    __half2* xw = (__half2*)(xh + (size_t)node * 64 + oct * 8);
#pragma unroll
    for (int i = 0; i < 4; ++i) {
        const float2 v = xr[i];
        xw[i] = __floats2half2_rn(v.x * dv, v.y * dv);
    }
}

// ---------------- aggregation: agg[d] = dv*(sum_{s in N(d)} xsc[s] + xsc[d]) ----------------
// xsc[n] = x[n]*dinv[n], so dv*xsc[d] = x[d]/deg[d]  (the self-loop term).
// One wave per node, lane = feature. Per edge: one 128B fp16 row gather (2 lines),
// col via coalesced load + readlane broadcast. No atomics, no LDS, no per-edge weight.
__device__ __forceinline__ int rlane_i(int v, int l) {
    return __builtin_amdgcn_readlane(v, l);
}

__global__ __launch_bounds__(256) void agg_rows(const __half* __restrict__ xh,
                                                const int* __restrict__ rowptr,
                                                const int* __restrict__ col,
                                                const float* __restrict__ dinv,
                                                float* __restrict__ agg, int n) {
    const int nd = blockIdx.x * 4 + (threadIdx.x >> 6);
    if (nd >= n) return;
    const int lane = threadIdx.x & 63;
    const int beg = rowptr[nd];
    const int end = rowptr[nd + 1];
    const float dv = dinv[nd];
    const float self = __half2float(xh[(size_t)nd * D + lane]);

    float a0 = 0.f, a1 = 0.f, a2 = 0.f, a3 = 0.f;
    for (int j = beg; j < end; j += 64) {
        const int chunk = min(end - j, 64);
        const int c = (lane < chunk) ? col[j + lane] : 0;   // coalesced 4B/lane
        int t = 0;
        for (; t + 7 < chunk; t += 8) {
            const int s0 = rlane_i(c, t + 0), s1 = rlane_i(c, t + 1);
            const int s2 = rlane_i(c, t + 2), s3 = rlane_i(c, t + 3);
            const int s4 = rlane_i(c, t + 4), s5 = rlane_i(c, t + 5);
            const int s6 = rlane_i(c, t + 6), s7 = rlane_i(c, t + 7);
            a0 += __half2float(xh[(size_t)s0 * D + lane]);
            a1 += __half2float(xh[(size_t)s1 * D + lane]);
            a2 += __half2float(xh[(size_t)s2 * D + lane]);
            a3 += __half2float(xh[(size_t)s3 * D + lane]);
            a0 += __half2float(xh[(size_t)s4 * D + lane]);
            a1 += __half2float(xh[(size_t)s5 * D + lane]);
            a2 += __half2float(xh[(size_t)s6 * D + lane]);
            a3 += __half2float(xh[(size_t)s7 * D + lane]);
        }
        for (; t < chunk; ++t) {
            const int s0 = rlane_i(c, t);
            a0 += __half2float(xh[(size_t)s0 * D + lane]);
        }
    }
    // FIX vs R7: self enters the inner sum UNSCALED: agg = dv*(sum + xsc_d)
    const float sum = (a0 + a1) + (a2 + a3) + self;
    agg[(size_t)nd * D + lane] = dv * sum;
}

// ---------------- GEMM: r = relu(agg @ W + b); write fp32 or scaled-fp16 ----------------
__device__ __forceinline__ float rlane_ff(float v, int l) {
    return __int_as_float(__builtin_amdgcn_readlane(__float_as_int(v), l));
}

template <bool SCALED_HALF_OUT>
__global__ __launch_bounds__(256) void gemm64(const float* __restrict__ aggs,
                                              const float* __restrict__ W,
                                              const float* __restrict__ bias,
                                              const float* __restrict__ dinv,
                                              float* __restrict__ out,
                                              __half* __restrict__ outh, int n) {
    const int lane = threadIdx.x & 63;
    const int gwave = (blockIdx.x * blockDim.x + threadIdx.x) >> 6;
    const int nwaves = (gridDim.x * blockDim.x) >> 6;
    float wcol[64];
#pragma unroll
    for (int k = 0; k < 64; ++k) wcol[k] = W[k * 64 + lane];
    const float bv = bias[lane];

    for (int nd = gwave; nd < n; nd += nwaves) {
        const float a = aggs[(size_t)nd * D + lane];   // lane holds feature `lane`
        float g0 = 0.f, g1 = 0.f, g2 = 0.f, g3 = 0.f;
#pragma unroll
        for (int k = 0; k < 64; k += 4) {
            g0 = fmaf(rlane_ff(a, k + 0), wcol[k + 0], g0);
            g1 = fmaf(rlane_ff(a, k + 1), wcol[k + 1], g1);
            g2 = fmaf(rlane_ff(a, k + 2), wcol[k + 2], g2);
            g3 = fmaf(rlane_ff(a, k + 3), wcol[k + 3], g3);
        }
        const float r = fmaxf((g0 + g1) + (g2 + g3) + bv, 0.f);
        if (SCALED_HALF_OUT)
            outh[(size_t)nd * D + lane] = __float2half(r * dinv[nd]);  // pre-scaled layer-2 input
        else
            out[(size_t)nd * D + lane] = r;                            // final fp32 output
    }
}

extern "C" void kernel_launch(void* const* d_in, const int* in_sizes, int n_in,
                              void* d_out, int out_size, void* d_ws, size_t ws_size,
                              hipStream_t stream) {
    const float* feature = (const float*)d_in[0];
    const int*   edges   = (const int*)d_in[1];   // [2, E] flat: src then dst
    const float* W1      = (const float*)d_in[2];
    const float* b1      = (const float*)d_in[3];
    const float* W2      = (const float*)d_in[4];
    const float* b2      = (const float*)d_in[5];
    float* out = (float*)d_out;

    const int* src = edges;
    const int* dst = edges + N_EDGES;

    // workspace layout
    char* w = (char*)d_ws;
    int*    gcount  = (int*)w;    w += sizeof(int) * (NB * 8);        // 16384
    int*    subbase = (int*)w;    w += sizeof(int) * (NB * 8 + 1);    // 16385
    int*    cursor  = (int*)w;    w += sizeof(int) * (NB * 8);
    int*    rowptr  = (int*)w;    w += sizeof(int) * (N_NODES + 1);
    float*  dinv    = (float*)w;  w += sizeof(float) * (N_NODES);
    int*    part    = (int*)w;    w += sizeof(int) * (N_EDGES);          // 6.4MB
    int*    colA    = (int*)w;    w += sizeof(int) * (N_EDGES);          // 6.4MB
    __half* xh      = (__half*)w; w += sizeof(__half) * ((size_t)N_NODES * D);  // 12.8MB
    __half* y1h     = (__half*)w; w += sizeof(__half) * ((size_t)N_NODES * D);  // 12.8MB
    float*  aggsA   = (float*)w;  w += sizeof(float) * ((size_t)N_NODES * D);   // 25.6MB

    // ---- partition + CSR + scaled-fp16 features (once) ----
    zero_int<<<(NB * 8 + 255) / 256, 256, 0, stream>>>(gcount, NB * 8);
    bucket_count<<<AB_BLOCKS, 256, 0, stream>>>(dst, gcount);
    scan16k<<<1, 1024, 0, stream>>>(gcount, subbase, cursor);
    partition_edges<<<AB_BLOCKS, 256, 0, stream>>>(src, dst, cursor, part);
    bucket_csr<<<NB_USED, 256, 0, stream>>>(subbase, part, colA, rowptr, dinv);
    convert_scale<<<(N_NODES * 8 + 255) / 256, 256, 0, stream>>>(feature, dinv, xh);

    const int agg_blocks = (N_NODES + 3) / 4;

    // ---- layer 1 ----
    agg_rows<<<agg_blocks, 256, 0, stream>>>(xh, rowptr, colA, dinv, aggsA, N_NODES);
    gemm64<true><<<2048, 256, 0, stream>>>(aggsA, W1, b1, dinv, nullptr, y1h, N_NODES);

    // ---- layer 2 ----
    agg_rows<<<agg_blocks, 256, 0, stream>>>(y1h, rowptr, colA, dinv, aggsA, N_NODES);
    gemm64<false><<<2048, 256, 0, stream>>>(aggsA, W2, b2, dinv, out, nullptr, N_NODES);
}